// Round 1
// baseline (132.708 us; speedup 1.0000x reference)
//
#include <hip/hip_runtime.h>
#include <hip/hip_bf16.h>
#include <hip/hip_fp16.h>

// NT-Xent: B=4096, D=128, N=8192, TEMP=0.5, label(i) = i ^ 4096
#define NB   4096
#define NTOT 8192
#define DD   128

typedef __attribute__((ext_vector_type(8))) _Float16 f16x8;
typedef __attribute__((ext_vector_type(4))) float    f32x4;

#if defined(__has_builtin)
#if __has_builtin(__builtin_amdgcn_exp2f)
#define EXP2F(x) __builtin_amdgcn_exp2f(x)
#else
#define EXP2F(x) exp2f(x)
#endif
#else
#define EXP2F(x) exp2f(x)
#endif

// e = exp(s - 2), s = dot * 2  ->  exp2(dot * 2*log2e - 2*log2e)
#define SCALE_ 2.8853900817779268f
#define BIAS_  (-2.8853900817779268f)

// ---------------- kernel 1: row-normalize, fp32 -> f16 ----------------
__global__ void knorm(const float* __restrict__ zi, const float* __restrict__ zj,
                      _Float16* __restrict__ zn) {
  int wave = threadIdx.x >> 6, lane = threadIdx.x & 63;
  int row = (blockIdx.x << 2) + wave;            // 2048 blocks * 4 rows
  const float* src = (row < NB) ? (zi + (size_t)row * DD)
                                : (zj + (size_t)(row - NB) * DD);
  float2 v = ((const float2*)src)[lane];         // 2 floats per lane
  float ss = v.x * v.x + v.y * v.y;
#pragma unroll
  for (int m = 1; m < 64; m <<= 1) ss += __shfl_xor(ss, m, 64);
  float inv = 1.0f / fmaxf(sqrtf(ss), 1e-8f);
  struct H2 { _Float16 x, y; } hv;
  hv.x = (_Float16)(v.x * inv);
  hv.y = (_Float16)(v.y * inv);
  ((unsigned int*)(zn + (size_t)row * DD))[lane] = __builtin_bit_cast(unsigned int, hv);
}

// ---------------- kernel 2: sim GEMM + streaming exp-sum ----------------
// grid = 64 rowblocks * 16 col chunks = 1024 blocks, 256 thr (4 waves)
// block: rows rb*128..+127 (wave w: rows +32w..+32w+31 as two 16-row strips),
//        cols chunk*512..+511 (32 tiles of 16)
__global__ __launch_bounds__(256) void kmain(const _Float16* __restrict__ zn,
                                             float* __restrict__ rowsum,
                                             float* __restrict__ slabel) {
  int rb    = blockIdx.x >> 4;
  int chunk = blockIdx.x & 15;
  int wave  = threadIdx.x >> 6;
  int lane  = threadIdx.x & 63;
  int q = lane >> 4;        // 0..3
  int c = lane & 15;        // 0..15
  int d = c - (q << 2);     // reg r contributes diag/label when d == r
  int rowbase = rb * 128 + wave * 32;

  // A fragments for 2 strips, K=128 (4 k-frags of 32), kept in VGPRs
  f16x8 a[2][4];
#pragma unroll
  for (int s = 0; s < 2; s++) {
    const _Float16* p = zn + (size_t)(rowbase + s * 16 + c) * DD + q * 8;
#pragma unroll
    for (int kk = 0; kk < 4; kk++) a[s][kk] = *(const f16x8*)(p + kk * 32);
  }

  float part[2][4] = {{0.f, 0.f, 0.f, 0.f}, {0.f, 0.f, 0.f, 0.f}};
  int colchunk = chunk * 512;

  for (int ct = 0; ct < 32; ct++) {
    int colbase = colchunk + ct * 16;
    f16x8 b[4];
    const _Float16* p = zn + (size_t)(colbase + c) * DD + q * 8;
#pragma unroll
    for (int kk = 0; kk < 4; kk++) b[kk] = *(const f16x8*)(p + kk * 32);

#pragma unroll
    for (int s = 0; s < 2; s++) {
      int sbase = rowbase + s * 16;
      f32x4 acc = {0.f, 0.f, 0.f, 0.f};
#pragma unroll
      for (int kk = 0; kk < 4; kk++)
        acc = __builtin_amdgcn_mfma_f32_16x16x32_f16(a[s][kk], b[kk], acc, 0, 0, 0);

      // C/D layout: col = lane&15, row = (lane>>4)*4 + reg   (guide §3, m89/m91)
      bool isdiag = (colbase == sbase);
      bool islab  = (colbase == (sbase ^ NB));
      if (islab) {
        // element (m=4q+r, n=c) is the label value for global row sbase+c when c==4q+r
        float lv = 0.f; bool has = false;
#pragma unroll
        for (int r = 0; r < 4; r++)
          if (d == r) { lv = acc[r] * 2.0f; has = true; }
        if (has) slabel[sbase + c] = lv;   // exactly one writer per row
      }
#pragma unroll
      for (int r = 0; r < 4; r++) {
        float e = EXP2F(fmaf(acc[r], SCALE_, BIAS_));
        if (isdiag && d == r) e = 0.f;     // exclude self-similarity
        part[s][r] += e;
      }
    }
  }

  // reduce exp-partials across the 16 lanes (same row, different cols)
#pragma unroll
  for (int s = 0; s < 2; s++)
#pragma unroll
    for (int r = 0; r < 4; r++) {
      float v = part[s][r];
      v += __shfl_xor(v, 1, 64);
      v += __shfl_xor(v, 2, 64);
      v += __shfl_xor(v, 4, 64);
      v += __shfl_xor(v, 8, 64);
      if (c == 0) atomicAdd(&rowsum[rowbase + s * 16 + (q << 2) + r], v);
    }
}

// ---------------- kernel 3: finalize scalar loss ----------------
__global__ void kfinal(const float* __restrict__ rowsum,
                       const float* __restrict__ slabel,
                       float* __restrict__ out) {
  int tid = threadIdx.x;  // 256 threads, 1 block
  float acc = 0.f;
  for (int i = tid; i < NTOT; i += 256)
    acc += 2.0f + logf(rowsum[i]) - slabel[i];  // logsumexp - s_label
#pragma unroll
  for (int m = 1; m < 64; m <<= 1) acc += __shfl_xor(acc, m, 64);
  __shared__ float ws[4];
  if ((tid & 63) == 0) ws[tid >> 6] = acc;
  __syncthreads();
  if (tid == 0) out[0] = (ws[0] + ws[1] + ws[2] + ws[3]) / (float)NTOT;
}

extern "C" void kernel_launch(void* const* d_in, const int* in_sizes, int n_in,
                              void* d_out, int out_size, void* d_ws, size_t ws_size,
                              hipStream_t stream) {
  const float* zi = (const float*)d_in[0];
  const float* zj = (const float*)d_in[1];
  float* out = (float*)d_out;

  char* ws = (char*)d_ws;
  const size_t ZN_BYTES = (size_t)NTOT * DD * sizeof(_Float16);  // 2 MiB
  _Float16* zn   = (_Float16*)ws;
  float* rowsum  = (float*)(ws + ZN_BYTES);
  float* slabel  = (float*)(ws + ZN_BYTES + NTOT * sizeof(float));

  hipMemsetAsync(rowsum, 0, NTOT * sizeof(float), stream);  // ws is poisoned 0xAA
  knorm<<<NTOT / 4, 256, 0, stream>>>(zi, zj, zn);
  kmain<<<(NTOT / 128) * 16, 256, 0, stream>>>(zn, rowsum, slabel);
  kfinal<<<1, 256, 0, stream>>>(rowsum, slabel, out);
}